// Round 13
// baseline (199.384 us; speedup 1.0000x reference)
//
#include <hip/hip_runtime.h>
#include <hip/hip_bf16.h>

#define B_ 8
#define C_ 320
#define N_ 13824      // 24^3
#define L_ 77
#define LP 80         // L padded for 16-col tiles
#define LV 96         // L padded for K=96 contraction
#define CTXD 768
#define CPG 10        // channels per group (320/32)
#define EPS_ 1e-5f
#define SCALE_ 0.05590169943749474f   // 320^-0.5

typedef __attribute__((__ext_vector_type__(4))) float f32x4;
typedef __attribute__((__ext_vector_type__(8))) short s16x8;
typedef __attribute__((__ext_vector_type__(4))) unsigned short u16x4;

// ws byte offsets
#define WS_ACCUM 0              // f32[8][32][2] = 2048 B
#define WS_T     2048           // f32[8][80]    = 2560 B
#define WS_KST   4608           // bf16[8][80][320] = 409600 B  (k scaled, [l][o])
#define WS_VST   414208         // bf16[8][80][320]             (v, [l][o])
#define WS_K2F   823808         // bf16[8][5][10][512]          (k2 fragment-contig)
#define WS_V2    1233408        // bf16[8][320][96]             (Wo v, [c][l])
#define WS_WQT   1724928        // bf16[320][320]  Wq transposed [c][o]
#define WS_WO    1929728        // bf16[320][320]  Wo [c'][o]
#define WS_WGL   2134528        // bf16[8][13824][96] = 21233664 B (softmax weights)
#define WS_XT    23368192       // bf16[8][13824][320] = 70778880 B (x transposed)

__device__ __forceinline__ unsigned short f2bf(float f) {
  union { float f; unsigned u; } v; v.f = f;
  unsigned r = v.u + 0x7FFFu + ((v.u >> 16) & 1u);
  return (unsigned short)(r >> 16);
}
__device__ __forceinline__ float bf2f(unsigned short s) {
  union { unsigned u; float f; } v; v.u = ((unsigned)s) << 16;
  return v.f;
}
// load 8 consecutive f32 -> bf16x8 fragment
__device__ __forceinline__ s16x8 cvt8(const float* p) {
  f32x4 a = *reinterpret_cast<const f32x4*>(p);
  f32x4 b = *reinterpret_cast<const f32x4*>(p + 4);
  s16x8 r;
  r[0] = (short)f2bf(a[0]); r[1] = (short)f2bf(a[1]);
  r[2] = (short)f2bf(a[2]); r[3] = (short)f2bf(a[3]);
  r[4] = (short)f2bf(b[0]); r[5] = (short)f2bf(b[1]);
  r[6] = (short)f2bf(b[2]); r[7] = (short)f2bf(b[3]);
  return r;
}
__device__ __forceinline__ f32x4 MFMA(s16x8 a, s16x8 b, f32x4 c) {
  return __builtin_amdgcn_mfma_f32_16x16x32_bf16(a, b, c, 0, 0, 0);
}

// ---------------- PREP: wconv (blocks 0..399) + kv1 l-split (blocks 400..599) --------
__global__ __launch_bounds__(256) void prep_kernel(const float* __restrict__ Wq,
                                                   const float* __restrict__ Wo,
                                                   const float* __restrict__ ctx,
                                                   const float* __restrict__ Wk,
                                                   const float* __restrict__ bk,
                                                   const float* __restrict__ Wv,
                                                   const float* __restrict__ bv,
                                                   unsigned short* __restrict__ wqT,
                                                   unsigned short* __restrict__ wo_bf,
                                                   unsigned short* __restrict__ kst,
                                                   unsigned short* __restrict__ vst,
                                                   float* __restrict__ zws) {
  int bid = blockIdx.x;
  if (bid < 400) {
    int t = bid * 256 + threadIdx.x;
    if (t >= C_ * C_) return;
    int o = t / C_, c = t - o * C_;
    wqT[c * C_ + o] = f2bf(Wq[t]);
    wo_bf[t] = f2bf(Wo[t]);
    return;
  }
  int kb = bid - 400;                       // 0..199
  { int t = kb * 256 + threadIdx.x; if (t < 1152) zws[t] = 0.f; }
  int lt = kb % 5;                          // l-tile 0..4
  int kb5 = kb / 5;                         // 0..39
  int b = kb5 / 5;
  int oc = kb5 % 5;                         // 64-row chunk of outputs
  int w = threadIdx.x >> 6, lane = threadIdx.x & 63;
  int r = lane & 15, h = lane >> 4;
  int o_row = oc * 64 + w * 16 + r;         // A-fragment row
  int l = lt * 16 + r;                      // B col / D col
  bool lok = (l < L_);
  f32x4 ak = {}, av = {};
  for (int ks = 0; ks < 24; ++ks) {
    int c0 = ks * 32 + h * 8;
    s16x8 aWk = cvt8(Wk + o_row * CTXD + c0);
    s16x8 aWv = cvt8(Wv + o_row * CTXD + c0);
    s16x8 bfr = {0,0,0,0,0,0,0,0};
    if (lok) bfr = cvt8(ctx + (b * L_ + l) * CTXD + c0);
    ak = MFMA(aWk, bfr, ak);
    av = MFMA(aWv, bfr, av);
  }
#pragma unroll
  for (int j = 0; j < 4; ++j) {
    int o = oc * 64 + w * 16 + h * 4 + j;
    float bkv = bk[o], bvv = bv[o];
    unsigned short kw = lok ? f2bf(SCALE_ * (ak[j] + bkv)) : (unsigned short)0;
    unsigned short vw = lok ? f2bf(av[j] + bvv) : (unsigned short)0;
    kst[(b * LP + l) * C_ + o] = kw;
    vst[(b * LP + l) * C_ + o] = vw;
  }
}

// ---------------- KV2: k2F (fragment-contig) = Wq^T k_s; v2[c][l] = Wo v_s; t[l] -----
__global__ __launch_bounds__(256) void kv2_kernel(const unsigned short* __restrict__ wqT,
                                                  const unsigned short* __restrict__ wo_bf,
                                                  const unsigned short* __restrict__ kst,
                                                  const unsigned short* __restrict__ vst,
                                                  const float* __restrict__ bq,
                                                  float* __restrict__ tbuf,
                                                  unsigned short* __restrict__ k2F,
                                                  unsigned short* __restrict__ v2) {
  int b = blockIdx.x / 5;
  int cc = blockIdx.x % 5;
  int w = threadIdx.x >> 6, lane = threadIdx.x & 63;
  int r = lane & 15, h = lane >> 4;
  int c_row = cc * 64 + w * 16 + r;
  f32x4 a2[5] = {}, av[5] = {};
#pragma unroll
  for (int ks = 0; ks < 10; ++ks) {
    int o0 = ks * 32 + h * 8;
    s16x8 aq = *reinterpret_cast<const s16x8*>(wqT + c_row * C_ + o0);
    s16x8 ao = *reinterpret_cast<const s16x8*>(wo_bf + c_row * C_ + o0);
#pragma unroll
    for (int nt = 0; nt < 5; ++nt) {
      int l = nt * 16 + r;
      s16x8 bk_ = *reinterpret_cast<const s16x8*>(kst + (b * LP + l) * C_ + o0);
      s16x8 bv_ = *reinterpret_cast<const s16x8*>(vst + (b * LP + l) * C_ + o0);
      a2[nt] = MFMA(aq, bk_, a2[nt]);
      av[nt] = MFMA(ao, bv_, av[nt]);
    }
  }
#pragma unroll
  for (int j = 0; j < 4; ++j) {
    int c = cc * 64 + w * 16 + h * 4 + j;     // output channel (D row)
    int ks2 = c >> 5, h2 = (c >> 3) & 3, j2 = c & 7;
#pragma unroll
    for (int nt = 0; nt < 5; ++nt) {
      int l = nt * 16 + r;                    // D col
      // k2 fragment layout: [b][nt][ks][lane = h2*16 + r][j2]; wave load = 1KB contig
      k2F[(((b * 5 + nt) * 10 + ks2) << 9) + ((h2 * 16 + r) << 3) + j2] = f2bf(a2[nt][j]);
      v2[(b * C_ + c) * LV + l] = f2bf(av[nt][j]);
    }
  }
  // zero v2 pad cols l in [80,96)
  {
    int c = cc * 64 + w * 16 + (lane >> 2);
    int l = 80 + (lane & 3) * 4;
    unsigned long long* p = (unsigned long long*)(v2 + ((long)(b * C_ + c)) * LV + l);
    *p = 0ull;
  }
  // t[l] = sum_o bq[o] * k_s[l][o]
  if (cc == 0 && threadIdx.x < LP) {
    int l = threadIdx.x;
    float acc = 0.f;
    for (int o8 = 0; o8 < C_; o8 += 8) {
      s16x8 kv = *reinterpret_cast<const s16x8*>(kst + (b * LP + l) * C_ + o8);
#pragma unroll
      for (int j = 0; j < 8; ++j) acc += bq[o8 + j] * bf2f((unsigned short)kv[j]);
    }
    tbuf[b * LP + l] = acc;
  }
}

// ---------------- FUSED-S: LDS transpose + xT emit + GEMM-S + softmax ----------------
// Emits BOTH the softmax weights w[b][n][96] and the transposed xT[b][n][c] bf16
// (contiguous b128 stores from the already-staged tile; drain under the MFMA phase).
__global__ __launch_bounds__(256)
__attribute__((amdgpu_waves_per_eu(2, 3)))
void fusedS_kernel(const float* __restrict__ x,
                   const unsigned short* __restrict__ k2F,
                   const float* __restrict__ tbuf,
                   unsigned short* __restrict__ wgl,
                   unsigned short* __restrict__ xT) {
  __shared__ __align__(16) unsigned short tile[64][344];   // 44032 B (pad: 2-way-free)
  int bid = blockIdx.x;        // 1728 = 8 (XCD-batch) x 216 tiles
  int b = bid & 7;
  int n0 = (bid >> 3) * 64;
  int tid = threadIdx.x;
  int w = tid >> 6, lane = tid & 63, r = lane & 15, h = lane >> 4;
  const unsigned short* k2f = k2F + ((long)b * 50 << 9);

  // k2F chunk-0 preload issued FIRST: its L2 latency hides under the whole stage phase
  s16x8 kfA[5], kfB[5];
#pragma unroll
  for (int nt = 0; nt < 5; ++nt)
    kfA[nt] = *reinterpret_cast<const s16x8*>(k2f + ((nt * 10) << 9) + (lane << 3));

  // ---- stage x tile transposed into LDS: load ALL 20 f32x4 first (deep MLP) ----
  {
    int s_ = tid & 15;          // n-quad
    int cp = tid >> 4;          // channel pair
    const float* xb = x + (long)b * C_ * N_ + n0 + s_ * 4;
    f32x4 va[10], vb[10];
#pragma unroll
    for (int it = 0; it < 10; ++it) {
      const float* p = xb + (long)(it * 32 + cp * 2) * N_;
      va[it] = *reinterpret_cast<const f32x4*>(p);
      vb[it] = *reinterpret_cast<const f32x4*>(p + N_);
    }
#pragma unroll
    for (int it = 0; it < 10; ++it) {
      int c = it * 32 + cp * 2;
#pragma unroll
      for (int q = 0; q < 4; ++q) {
        unsigned pk = (unsigned)f2bf(va[it][q]) | ((unsigned)f2bf(vb[it][q]) << 16);
        *reinterpret_cast<unsigned*>(&tile[s_ * 4 + q][c]) = pk;
      }
    }
  }
  __syncthreads();

  // ---- emit xT bf16 (contiguous b128 stores; overlap with GEMM-S below) ----
  {
    int row = tid >> 2, part = tid & 3;
    const s16x8* src = reinterpret_cast<const s16x8*>(&tile[row][part * 80]);
    s16x8* dst = reinterpret_cast<s16x8*>(xT + ((long)b * N_ + n0 + row) * C_ + part * 80);
#pragma unroll
    for (int k = 0; k < 10; ++k) dst[k] = src[k];
  }

  // ---- GEMM-S: s[16 n/wave][80 l], K=320; A from LDS, B = k2F 1-ahead pipeline ----
  f32x4 sacc[5] = {};
#define SCHUNK(KS, KC, KN)                                                      \
  {                                                                             \
    s16x8 a = *reinterpret_cast<const s16x8*>(&tile[w * 16 + r][KS * 32 + h * 8]); \
    if (KS < 9) {                                                               \
      _Pragma("unroll") for (int nt = 0; nt < 5; ++nt)                          \
          KN[nt] = *reinterpret_cast<const s16x8*>(                             \
              k2f + ((nt * 10 + KS + 1) << 9) + (lane << 3));                   \
    }                                                                           \
    _Pragma("unroll") for (int nt = 0; nt < 5; ++nt)                            \
      sacc[nt] = MFMA(a, KC[nt], sacc[nt]);                                     \
  }
  SCHUNK(0, kfA, kfB) SCHUNK(1, kfB, kfA) SCHUNK(2, kfA, kfB)
  SCHUNK(3, kfB, kfA) SCHUNK(4, kfA, kfB) SCHUNK(5, kfB, kfA)
  SCHUNK(6, kfA, kfB) SCHUNK(7, kfB, kfA) SCHUNK(8, kfA, kfB)
  SCHUNK(9, kfB, kfA)
#undef SCHUNK

  // ---- + t, softmax over l; write w rows (96 cols, pad zeroed) ----
#pragma unroll
  for (int nt = 0; nt < 5; ++nt) {
    float tl = tbuf[b * LP + nt * 16 + r];
#pragma unroll
    for (int j = 0; j < 4; ++j) sacc[nt][j] += tl;
  }
  unsigned short* wrow = wgl + ((long)b * N_ + n0) * 96;
  bool maskpad = (r >= 13);   // col 64+r >= 77
#pragma unroll
  for (int j = 0; j < 4; ++j) {
    float m = -1e30f;
#pragma unroll
    for (int nt = 0; nt < 5; ++nt) {
      float v = (nt == 4 && maskpad) ? -1e30f : sacc[nt][j];
      m = fmaxf(m, v);
    }
    for (int d = 1; d < 16; d <<= 1) m = fmaxf(m, __shfl_xor(m, d));
    float e[5]; float sum = 0.f;
#pragma unroll
    for (int nt = 0; nt < 5; ++nt) {
      float v = (nt == 4 && maskpad) ? 0.f : __expf(sacc[nt][j] - m);
      e[nt] = v; sum += v;
    }
    for (int d = 1; d < 16; d <<= 1) sum += __shfl_xor(sum, d);
    float inv = 1.f / sum;
    int n = w * 16 + h * 4 + j;
#pragma unroll
    for (int nt = 0; nt < 5; ++nt) wrow[(long)n * 96 + nt * 16 + r] = f2bf(e[nt] * inv);
  }
  // zero pad cols 80..95 of this wave's 16 rows (K=96 contraction pad)
  {
    int row = w * 16 + (lane >> 2);
    int c0 = 80 + (lane & 3) * 4;
    *reinterpret_cast<unsigned long long*>(wrow + (long)row * 96 + c0) = 0ull;
  }
}

// ---------------- MAIN-H: barrier-free GEMM h = v2 . w^T + epilogue -----------------
// Residual now from packed xT bf16 (contiguous b64 loads, R10-proven; replaces the
// 80-scalar-strided-f32-load epilogue that was mainH's segment-request hot spot).
__global__ __launch_bounds__(256)
__attribute__((amdgpu_waves_per_eu(2, 3)))
void mainH_kernel(const unsigned short* __restrict__ xT,
                  const unsigned short* __restrict__ wgl,
                  const unsigned short* __restrict__ v2,
                  const float* __restrict__ bo,
                  float* __restrict__ accum,
                  float* __restrict__ hout) {
  __shared__ float ch[C_][2];
  int bid = blockIdx.x;        // 1728 = 8 x 216
  int b = bid & 7;
  int n0 = (bid >> 3) * 64;
  int tid = threadIdx.x;
  int w = tid >> 6, lane = tid & 63, r = lane & 15, h = lane >> 4;
  const unsigned short* wb = wgl + ((long)b * N_ + n0) * 96;
  const unsigned short* v2b = v2 + ((long)b * C_ + w * 80) * LV;
  const unsigned short* xTb = xT + ((long)b * N_ + n0) * C_;

  f32x4 acc[4][5] = {};   // [nt][mt]: wave covers 80 c x 64 n
#pragma unroll
  for (int ks = 0; ks < 3; ++ks) {
    s16x8 bf[4];
#pragma unroll
    for (int nt = 0; nt < 4; ++nt)
      bf[nt] = *reinterpret_cast<const s16x8*>(wb + (long)(nt * 16 + r) * 96 + ks * 32 + h * 8);
#pragma unroll
    for (int mt = 0; mt < 5; ++mt) {
      s16x8 va = *reinterpret_cast<const s16x8*>(v2b + (long)(mt * 16 + r) * LV + ks * 32 + h * 8);
#pragma unroll
      for (int nt = 0; nt < 4; ++nt) acc[nt][mt] = MFMA(va, bf[nt], acc[nt][mt]);
    }
  }
  // ---- epilogue: + bo + residual (bf16 xT, b64 contiguous), packed store, stats ----
#pragma unroll
  for (int mt = 0; mt < 5; ++mt) {
    int cb = w * 80 + mt * 16 + h * 4;
    float bov[4];
#pragma unroll
    for (int j = 0; j < 4; ++j) bov[j] = bo[cb + j];
    float sv[4] = {0.f, 0.f, 0.f, 0.f}, sq[4] = {0.f, 0.f, 0.f, 0.f};
#pragma unroll
    for (int nt = 0; nt < 4; ++nt) {
      int n = nt * 16 + r;
      u16x4 xr = *reinterpret_cast<const u16x4*>(xTb + (long)n * C_ + cb);
#pragma unroll
      for (int j = 0; j < 4; ++j) {
        float val = acc[nt][mt][j] + bov[j] + bf2f(xr[j]);
        // bf16 packed store: chunk 2048 elems; bf16 sits in first 4 KB of the
        // chunk's 8 KB f32 region (self-contained for norm blocks)
        long e = ((long)b * C_ + cb + j) * N_ + n0 + n;
        *reinterpret_cast<unsigned short*>(
            (char*)hout + ((e >> 11) << 13) + ((e & 2047) << 1)) = f2bf(val);
        sv[j] += val; sq[j] += val * val;
      }
    }
#pragma unroll
    for (int j = 0; j < 4; ++j) {
      for (int d = 1; d < 16; d <<= 1) {
        sv[j] += __shfl_xor(sv[j], d);
        sq[j] += __shfl_xor(sq[j], d);
      }
      if (r == 0) { ch[cb + j][0] = sv[j]; ch[cb + j][1] = sq[j]; }
    }
  }
  __syncthreads();
  if (tid < 32) {
    float s0 = 0.f, s1 = 0.f;
#pragma unroll
    for (int i = 0; i < CPG; ++i) { s0 += ch[tid * CPG + i][0]; s1 += ch[tid * CPG + i][1]; }
    atomicAdd(&accum[b * 64 + tid * 2], s0);
    atomicAdd(&accum[b * 64 + tid * 2 + 1], s1);
  }
}

// ---------------- normalize + affine + swish: bf16 packed in -> f32 out -------------
__global__ __launch_bounds__(256) void norm_kernel(float* __restrict__ hout,
                                                   const float* __restrict__ accum,
                                                   const float* __restrict__ gamma,
                                                   const float* __restrict__ beta) {
  long idx0 = (long)blockIdx.x * 2048;
  int t = threadIdx.x;
  s16x8 hv = *reinterpret_cast<const s16x8*>((const char*)hout + idx0 * 4 + t * 16);
  __syncthreads();   // all bf16 reads complete before any f32 overwrite (intra-chunk)
  long idx = idx0 + (long)t * 8;
  int b = (int)(idx / ((long)C_ * N_));
  long rem = idx - (long)b * C_ * N_;
  int c = (int)(rem / N_);
  int g = c / CPG;
  float s0 = accum[b * 64 + g * 2], s1 = accum[b * 64 + g * 2 + 1];
  const float invc = 1.f / 138240.f;   // 1 / (CPG * N_)
  float mu = s0 * invc;
  float var = s1 * invc - mu * mu;
  float rstd = rsqrtf(var + EPS_);
  float ga = gamma[c], be = beta[c];
  f32x4 v0, v1;
#pragma unroll
  for (int q = 0; q < 4; ++q) {
    float y = (bf2f((unsigned short)hv[q]) - mu) * rstd * ga + be;
    v0[q] = y / (1.f + __expf(-y));
    float z = (bf2f((unsigned short)hv[q + 4]) - mu) * rstd * ga + be;
    v1[q] = z / (1.f + __expf(-z));
  }
  *reinterpret_cast<f32x4*>(hout + idx) = v0;
  *reinterpret_cast<f32x4*>(hout + idx + 4) = v1;
}

extern "C" void kernel_launch(void* const* d_in, const int* in_sizes, int n_in,
                              void* d_out, int out_size, void* d_ws, size_t ws_size,
                              hipStream_t stream) {
  const float* x     = (const float*)d_in[0];
  const float* ctx   = (const float*)d_in[1];
  const float* Wq    = (const float*)d_in[2];
  const float* bq    = (const float*)d_in[3];
  const float* Wk    = (const float*)d_in[4];
  const float* bk    = (const float*)d_in[5];
  const float* Wv    = (const float*)d_in[6];
  const float* bv    = (const float*)d_in[7];
  const float* Wo    = (const float*)d_in[8];
  const float* bo    = (const float*)d_in[9];
  const float* gamma = (const float*)d_in[10];
  const float* beta  = (const float*)d_in[11];
  float* out = (float*)d_out;
  char* ws = (char*)d_ws;

  float* accum = (float*)(ws + WS_ACCUM);
  float* tbuf  = (float*)(ws + WS_T);
  unsigned short* kst  = (unsigned short*)(ws + WS_KST);
  unsigned short* vst  = (unsigned short*)(ws + WS_VST);
  unsigned short* k2F  = (unsigned short*)(ws + WS_K2F);
  unsigned short* v2   = (unsigned short*)(ws + WS_V2);
  unsigned short* wqT  = (unsigned short*)(ws + WS_WQT);
  unsigned short* wo_b = (unsigned short*)(ws + WS_WO);
  unsigned short* wgl  = (unsigned short*)(ws + WS_WGL);
  unsigned short* xT   = (unsigned short*)(ws + WS_XT);

  prep_kernel<<<dim3(600), dim3(256), 0, stream>>>(Wq, Wo, ctx, Wk, bk, Wv, bv,
                                                   wqT, wo_b, kst, vst, (float*)ws);
  kv2_kernel<<<dim3(40), dim3(256), 0, stream>>>(wqT, wo_b, kst, vst, bq, tbuf, k2F, v2);
  fusedS_kernel<<<dim3(1728), dim3(256), 0, stream>>>(x, k2F, tbuf, wgl, xT);
  mainH_kernel<<<dim3(1728), dim3(256), 0, stream>>>(xT, wgl, v2, bo, accum, out);
  norm_kernel<<<dim3(17280), dim3(256), 0, stream>>>(out, accum, gamma, beta);
}

// Round 14
// 182.434 us; speedup vs baseline: 1.0929x; 1.0929x over previous
//
#include <hip/hip_runtime.h>
#include <hip/hip_bf16.h>

#define B_ 8
#define C_ 320
#define N_ 13824      // 24^3
#define L_ 77
#define LP 80         // L padded for 16-col tiles
#define LV 96         // L padded for K=96 contraction
#define CTXD 768
#define CPG 10        // channels per group (320/32)
#define EPS_ 1e-5f
#define SCALE_ 0.05590169943749474f   // 320^-0.5

typedef __attribute__((__ext_vector_type__(4))) float f32x4;
typedef __attribute__((__ext_vector_type__(8))) short s16x8;

// ws byte offsets
#define WS_ACCUM 0              // f32[8][32][2] = 2048 B
#define WS_T     2048           // f32[8][80]    = 2560 B
#define WS_KST   4608           // bf16[8][80][320] = 409600 B  (k scaled, [l][o])
#define WS_VST   414208         // bf16[8][80][320]             (v, [l][o])
#define WS_K2F   823808         // bf16[8][5][10][512]          (k2 fragment-contig)
#define WS_V2    1233408        // bf16[8][320][96]             (Wo v, [c][l])
#define WS_WQT   1724928        // bf16[320][320]  Wq transposed [c][o]
#define WS_WO    1929728        // bf16[320][320]  Wo [c'][o]
#define WS_WGL   2134528        // bf16[8][13824][96] = 21233664 B (softmax weights)

__device__ __forceinline__ unsigned short f2bf(float f) {
  union { float f; unsigned u; } v; v.f = f;
  unsigned r = v.u + 0x7FFFu + ((v.u >> 16) & 1u);
  return (unsigned short)(r >> 16);
}
__device__ __forceinline__ float bf2f(unsigned short s) {
  union { unsigned u; float f; } v; v.u = ((unsigned)s) << 16;
  return v.f;
}
// load 8 consecutive f32 -> bf16x8 fragment
__device__ __forceinline__ s16x8 cvt8(const float* p) {
  f32x4 a = *reinterpret_cast<const f32x4*>(p);
  f32x4 b = *reinterpret_cast<const f32x4*>(p + 4);
  s16x8 r;
  r[0] = (short)f2bf(a[0]); r[1] = (short)f2bf(a[1]);
  r[2] = (short)f2bf(a[2]); r[3] = (short)f2bf(a[3]);
  r[4] = (short)f2bf(b[0]); r[5] = (short)f2bf(b[1]);
  r[6] = (short)f2bf(b[2]); r[7] = (short)f2bf(b[3]);
  return r;
}
__device__ __forceinline__ f32x4 MFMA(s16x8 a, s16x8 b, f32x4 c) {
  return __builtin_amdgcn_mfma_f32_16x16x32_bf16(a, b, c, 0, 0, 0);
}

// ---------------- PREP: wconv (blocks 0..399) + kv1 l-split (blocks 400..599) --------
__global__ __launch_bounds__(256) void prep_kernel(const float* __restrict__ Wq,
                                                   const float* __restrict__ Wo,
                                                   const float* __restrict__ ctx,
                                                   const float* __restrict__ Wk,
                                                   const float* __restrict__ bk,
                                                   const float* __restrict__ Wv,
                                                   const float* __restrict__ bv,
                                                   unsigned short* __restrict__ wqT,
                                                   unsigned short* __restrict__ wo_bf,
                                                   unsigned short* __restrict__ kst,
                                                   unsigned short* __restrict__ vst,
                                                   float* __restrict__ zws) {
  int bid = blockIdx.x;
  if (bid < 400) {
    int t = bid * 256 + threadIdx.x;
    if (t >= C_ * C_) return;
    int o = t / C_, c = t - o * C_;
    wqT[c * C_ + o] = f2bf(Wq[t]);
    wo_bf[t] = f2bf(Wo[t]);
    return;
  }
  int kb = bid - 400;                       // 0..199
  { int t = kb * 256 + threadIdx.x; if (t < 1152) zws[t] = 0.f; }
  int lt = kb % 5;                          // l-tile 0..4
  int kb5 = kb / 5;                         // 0..39
  int b = kb5 / 5;
  int oc = kb5 % 5;                         // 64-row chunk of outputs
  int w = threadIdx.x >> 6, lane = threadIdx.x & 63;
  int r = lane & 15, h = lane >> 4;
  int o_row = oc * 64 + w * 16 + r;         // A-fragment row
  int l = lt * 16 + r;                      // B col / D col
  bool lok = (l < L_);
  f32x4 ak = {}, av = {};
  for (int ks = 0; ks < 24; ++ks) {
    int c0 = ks * 32 + h * 8;
    s16x8 aWk = cvt8(Wk + o_row * CTXD + c0);
    s16x8 aWv = cvt8(Wv + o_row * CTXD + c0);
    s16x8 bfr = {0,0,0,0,0,0,0,0};
    if (lok) bfr = cvt8(ctx + (b * L_ + l) * CTXD + c0);
    ak = MFMA(aWk, bfr, ak);
    av = MFMA(aWv, bfr, av);
  }
#pragma unroll
  for (int j = 0; j < 4; ++j) {
    int o = oc * 64 + w * 16 + h * 4 + j;
    float bkv = bk[o], bvv = bv[o];
    unsigned short kw = lok ? f2bf(SCALE_ * (ak[j] + bkv)) : (unsigned short)0;
    unsigned short vw = lok ? f2bf(av[j] + bvv) : (unsigned short)0;
    kst[(b * LP + l) * C_ + o] = kw;
    vst[(b * LP + l) * C_ + o] = vw;
  }
}

// ---------------- KV2: k2F (fragment-contig) = Wq^T k_s; v2[c][l] = Wo v_s; t[l] -----
__global__ __launch_bounds__(256) void kv2_kernel(const unsigned short* __restrict__ wqT,
                                                  const unsigned short* __restrict__ wo_bf,
                                                  const unsigned short* __restrict__ kst,
                                                  const unsigned short* __restrict__ vst,
                                                  const float* __restrict__ bq,
                                                  float* __restrict__ tbuf,
                                                  unsigned short* __restrict__ k2F,
                                                  unsigned short* __restrict__ v2) {
  int b = blockIdx.x / 5;
  int cc = blockIdx.x % 5;
  int w = threadIdx.x >> 6, lane = threadIdx.x & 63;
  int r = lane & 15, h = lane >> 4;
  int c_row = cc * 64 + w * 16 + r;
  f32x4 a2[5] = {}, av[5] = {};
#pragma unroll
  for (int ks = 0; ks < 10; ++ks) {
    int o0 = ks * 32 + h * 8;
    s16x8 aq = *reinterpret_cast<const s16x8*>(wqT + c_row * C_ + o0);
    s16x8 ao = *reinterpret_cast<const s16x8*>(wo_bf + c_row * C_ + o0);
#pragma unroll
    for (int nt = 0; nt < 5; ++nt) {
      int l = nt * 16 + r;
      s16x8 bk_ = *reinterpret_cast<const s16x8*>(kst + (b * LP + l) * C_ + o0);
      s16x8 bv_ = *reinterpret_cast<const s16x8*>(vst + (b * LP + l) * C_ + o0);
      a2[nt] = MFMA(aq, bk_, a2[nt]);
      av[nt] = MFMA(ao, bv_, av[nt]);
    }
  }
#pragma unroll
  for (int j = 0; j < 4; ++j) {
    int c = cc * 64 + w * 16 + h * 4 + j;     // output channel (D row)
    int ks2 = c >> 5, h2 = (c >> 3) & 3, j2 = c & 7;
#pragma unroll
    for (int nt = 0; nt < 5; ++nt) {
      int l = nt * 16 + r;                    // D col
      // k2 fragment layout: [b][nt][ks][lane = h2*16 + r][j2]; wave load = 1KB contig
      k2F[(((b * 5 + nt) * 10 + ks2) << 9) + ((h2 * 16 + r) << 3) + j2] = f2bf(a2[nt][j]);
      v2[(b * C_ + c) * LV + l] = f2bf(av[nt][j]);
    }
  }
  // zero v2 pad cols l in [80,96)
  {
    int c = cc * 64 + w * 16 + (lane >> 2);
    int l = 80 + (lane & 3) * 4;
    unsigned long long* p = (unsigned long long*)(v2 + ((long)(b * C_ + c)) * LV + l);
    *p = 0ull;
  }
  // t[l] = sum_o bq[o] * k_s[l][o]
  if (cc == 0 && threadIdx.x < LP) {
    int l = threadIdx.x;
    float acc = 0.f;
    for (int o8 = 0; o8 < C_; o8 += 8) {
      s16x8 kv = *reinterpret_cast<const s16x8*>(kst + (b * LP + l) * C_ + o8);
#pragma unroll
      for (int j = 0; j < 8; ++j) acc += bq[o8 + j] * bf2f((unsigned short)kv[j]);
    }
    tbuf[b * LP + l] = acc;
  }
}

// ---------------- FUSED-S: LDS transpose + GEMM-S + softmax -> w[b][n][96] bf16 ------
// LDS staging writes XOR-swizzled (off ^= row&48): 8-way write conflict -> 2-way free.
__global__ __launch_bounds__(256)
__attribute__((amdgpu_waves_per_eu(2, 3)))
void fusedS_kernel(const float* __restrict__ x,
                   const unsigned short* __restrict__ k2F,
                   const float* __restrict__ tbuf,
                   unsigned short* __restrict__ wgl) {
  __shared__ __align__(16) unsigned short tile[64][344];   // 44032 B (688 B rows)
  char* tb = (char*)&tile[0][0];
  int bid = blockIdx.x;        // 1728 = 8 (XCD-batch) x 216 tiles
  int b = bid & 7;
  int n0 = (bid >> 3) * 64;
  int tid = threadIdx.x;
  int w = tid >> 6, lane = tid & 63, r = lane & 15, h = lane >> 4;
  const unsigned short* k2f = k2F + ((long)b * 50 << 9);

  // k2F chunk-0 preload issued FIRST: its L2 latency hides under the whole stage phase
  s16x8 kfA[5], kfB[5];
#pragma unroll
  for (int nt = 0; nt < 5; ++nt)
    kfA[nt] = *reinterpret_cast<const s16x8*>(k2f + ((nt * 10) << 9) + (lane << 3));

  // ---- stage x tile transposed into LDS (deep-load batch, swizzled writes) ----
  {
    int s_ = tid & 15;          // n-quad
    int cp = tid >> 4;          // channel pair
    const float* xb = x + (long)b * C_ * N_ + n0 + s_ * 4;
    f32x4 va[10], vb[10];
#pragma unroll
    for (int it = 0; it < 10; ++it) {
      const float* p = xb + (long)(it * 32 + cp * 2) * N_;
      va[it] = *reinterpret_cast<const f32x4*>(p);
      vb[it] = *reinterpret_cast<const f32x4*>(p + N_);
    }
#pragma unroll
    for (int it = 0; it < 10; ++it) {
      int cbyte = (it * 32 + cp * 2) * 2;
#pragma unroll
      for (int q = 0; q < 4; ++q) {
        int row = s_ * 4 + q;
        unsigned pk = (unsigned)f2bf(va[it][q]) | ((unsigned)f2bf(vb[it][q]) << 16);
        *reinterpret_cast<unsigned*>(tb + row * 688 + (cbyte ^ (row & 48))) = pk;
      }
    }
  }
  __syncthreads();

  // ---- GEMM-S: s[16 n/wave][80 l], K=320; A from LDS (swizzled), B = k2F pipeline ----
  int arow = w * 16 + r;
  int abase = arow * 688;
  int akey = arow & 48;        // wave-uniform (= w<<4): read banks unchanged
  f32x4 sacc[5] = {};
#define SCHUNK(KS, KC, KN)                                                      \
  {                                                                             \
    s16x8 a = *reinterpret_cast<const s16x8*>(                                  \
        tb + abase + (((KS * 32 + h * 8) * 2) ^ akey));                         \
    if (KS < 9) {                                                               \
      _Pragma("unroll") for (int nt = 0; nt < 5; ++nt)                          \
          KN[nt] = *reinterpret_cast<const s16x8*>(                             \
              k2f + ((nt * 10 + KS + 1) << 9) + (lane << 3));                   \
    }                                                                           \
    _Pragma("unroll") for (int nt = 0; nt < 5; ++nt)                            \
      sacc[nt] = MFMA(a, KC[nt], sacc[nt]);                                     \
  }
  SCHUNK(0, kfA, kfB) SCHUNK(1, kfB, kfA) SCHUNK(2, kfA, kfB)
  SCHUNK(3, kfB, kfA) SCHUNK(4, kfA, kfB) SCHUNK(5, kfB, kfA)
  SCHUNK(6, kfA, kfB) SCHUNK(7, kfB, kfA) SCHUNK(8, kfA, kfB)
  SCHUNK(9, kfB, kfA)
#undef SCHUNK

  // ---- + t, softmax over l; write w rows (96 cols, pad zeroed) ----
#pragma unroll
  for (int nt = 0; nt < 5; ++nt) {
    float tl = tbuf[b * LP + nt * 16 + r];
#pragma unroll
    for (int j = 0; j < 4; ++j) sacc[nt][j] += tl;
  }
  unsigned short* wrow = wgl + ((long)b * N_ + n0) * 96;
  bool maskpad = (r >= 13);   // col 64+r >= 77
#pragma unroll
  for (int j = 0; j < 4; ++j) {
    float m = -1e30f;
#pragma unroll
    for (int nt = 0; nt < 5; ++nt) {
      float v = (nt == 4 && maskpad) ? -1e30f : sacc[nt][j];
      m = fmaxf(m, v);
    }
    for (int d = 1; d < 16; d <<= 1) m = fmaxf(m, __shfl_xor(m, d));
    float e[5]; float sum = 0.f;
#pragma unroll
    for (int nt = 0; nt < 5; ++nt) {
      float v = (nt == 4 && maskpad) ? 0.f : __expf(sacc[nt][j] - m);
      e[nt] = v; sum += v;
    }
    for (int d = 1; d < 16; d <<= 1) sum += __shfl_xor(sum, d);
    float inv = 1.f / sum;
    int n = w * 16 + h * 4 + j;
#pragma unroll
    for (int nt = 0; nt < 5; ++nt) wrow[(long)n * 96 + nt * 16 + r] = f2bf(e[nt] * inv);
  }
  // zero pad cols 80..95 of this wave's 16 rows (K=96 contraction pad)
  {
    int row = w * 16 + (lane >> 2);
    int c0 = 80 + (lane & 3) * 4;
    *reinterpret_cast<unsigned long long*>(wrow + (long)row * 96 + c0) = 0ull;
  }
}

// ---------------- MAIN-H: barrier-free GEMM h = v2 . w^T + epilogue -----------------
__global__ __launch_bounds__(256)
__attribute__((amdgpu_waves_per_eu(2, 3)))
void mainH_kernel(const float* __restrict__ x,
                  const unsigned short* __restrict__ wgl,
                  const unsigned short* __restrict__ v2,
                  const float* __restrict__ bo,
                  float* __restrict__ accum,
                  float* __restrict__ hout) {
  __shared__ float ch[C_][2];
  int bid = blockIdx.x;        // 1728 = 8 x 216
  int b = bid & 7;
  int n0 = (bid >> 3) * 64;
  int tid = threadIdx.x;
  int w = tid >> 6, lane = tid & 63, r = lane & 15, h = lane >> 4;
  const unsigned short* wb = wgl + ((long)b * N_ + n0) * 96;
  const unsigned short* v2b = v2 + ((long)b * C_ + w * 80) * LV;
  const float* xb = x + (long)b * C_ * N_ + n0;

  f32x4 acc[4][5] = {};   // [nt][mt]: wave covers 80 c x 64 n
#pragma unroll
  for (int ks = 0; ks < 3; ++ks) {
    s16x8 bf[4];
#pragma unroll
    for (int nt = 0; nt < 4; ++nt)
      bf[nt] = *reinterpret_cast<const s16x8*>(wb + (long)(nt * 16 + r) * 96 + ks * 32 + h * 8);
#pragma unroll
    for (int mt = 0; mt < 5; ++mt) {
      s16x8 va = *reinterpret_cast<const s16x8*>(v2b + (long)(mt * 16 + r) * LV + ks * 32 + h * 8);
#pragma unroll
      for (int nt = 0; nt < 4; ++nt) acc[nt][mt] = MFMA(va, bf[nt], acc[nt][mt]);
    }
  }
  // ---- epilogue: + bo + residual (f32, L3-hot), bf16 packed store, group stats ----
#pragma unroll
  for (int mt = 0; mt < 5; ++mt) {
    int cb = w * 80 + mt * 16 + h * 4;
    float bov[4];
#pragma unroll
    for (int j = 0; j < 4; ++j) bov[j] = bo[cb + j];
    float sv[4] = {0.f, 0.f, 0.f, 0.f}, sq[4] = {0.f, 0.f, 0.f, 0.f};
#pragma unroll
    for (int nt = 0; nt < 4; ++nt) {
      int n = nt * 16 + r;
#pragma unroll
      for (int j = 0; j < 4; ++j) {
        float val = acc[nt][mt][j] + bov[j] + xb[(long)(cb + j) * N_ + n];
        long e = ((long)b * C_ + cb + j) * N_ + n0 + n;
        *reinterpret_cast<unsigned short*>(
            (char*)hout + ((e >> 11) << 13) + ((e & 2047) << 1)) = f2bf(val);
        sv[j] += val; sq[j] += val * val;
      }
    }
#pragma unroll
    for (int j = 0; j < 4; ++j) {
      for (int d = 1; d < 16; d <<= 1) {
        sv[j] += __shfl_xor(sv[j], d);
        sq[j] += __shfl_xor(sq[j], d);
      }
      if (r == 0) { ch[cb + j][0] = sv[j]; ch[cb + j][1] = sq[j]; }
    }
  }
  __syncthreads();
  if (tid < 32) {
    float s0 = 0.f, s1 = 0.f;
#pragma unroll
    for (int i = 0; i < CPG; ++i) { s0 += ch[tid * CPG + i][0]; s1 += ch[tid * CPG + i][1]; }
    atomicAdd(&accum[b * 64 + tid * 2], s0);
    atomicAdd(&accum[b * 64 + tid * 2 + 1], s1);
  }
}

// ---------------- normalize + affine + swish: bf16 packed in -> f32 NT out ----------
// Nontemporal f32 stores: the final output is never re-read; keeping it out of L2/L3
// preserves x (141.6 MB) + hout (70.8) + wgl (21) < 256 MB L3-resident across replays.
__global__ __launch_bounds__(256) void norm_kernel(float* __restrict__ hout,
                                                   const float* __restrict__ accum,
                                                   const float* __restrict__ gamma,
                                                   const float* __restrict__ beta) {
  long idx0 = (long)blockIdx.x * 2048;
  int t = threadIdx.x;
  s16x8 hv = *reinterpret_cast<const s16x8*>((const char*)hout + idx0 * 4 + t * 16);
  __syncthreads();   // all bf16 reads complete before any f32 overwrite (intra-chunk)
  long idx = idx0 + (long)t * 8;
  int b = (int)(idx / ((long)C_ * N_));
  long rem = idx - (long)b * C_ * N_;
  int c = (int)(rem / N_);
  int g = c / CPG;
  float s0 = accum[b * 64 + g * 2], s1 = accum[b * 64 + g * 2 + 1];
  const float invc = 1.f / 138240.f;   // 1 / (CPG * N_)
  float mu = s0 * invc;
  float var = s1 * invc - mu * mu;
  float rstd = rsqrtf(var + EPS_);
  float ga = gamma[c], be = beta[c];
  f32x4 v0, v1;
#pragma unroll
  for (int q = 0; q < 4; ++q) {
    float y = (bf2f((unsigned short)hv[q]) - mu) * rstd * ga + be;
    v0[q] = y / (1.f + __expf(-y));
    float z = (bf2f((unsigned short)hv[q + 4]) - mu) * rstd * ga + be;
    v1[q] = z / (1.f + __expf(-z));
  }
  __builtin_nontemporal_store(v0, reinterpret_cast<f32x4*>(hout + idx));
  __builtin_nontemporal_store(v1, reinterpret_cast<f32x4*>(hout + idx + 4));
}

extern "C" void kernel_launch(void* const* d_in, const int* in_sizes, int n_in,
                              void* d_out, int out_size, void* d_ws, size_t ws_size,
                              hipStream_t stream) {
  const float* x     = (const float*)d_in[0];
  const float* ctx   = (const float*)d_in[1];
  const float* Wq    = (const float*)d_in[2];
  const float* bq    = (const float*)d_in[3];
  const float* Wk    = (const float*)d_in[4];
  const float* bk    = (const float*)d_in[5];
  const float* Wv    = (const float*)d_in[6];
  const float* bv    = (const float*)d_in[7];
  const float* Wo    = (const float*)d_in[8];
  const float* bo    = (const float*)d_in[9];
  const float* gamma = (const float*)d_in[10];
  const float* beta  = (const float*)d_in[11];
  float* out = (float*)d_out;
  char* ws = (char*)d_ws;

  float* accum = (float*)(ws + WS_ACCUM);
  float* tbuf  = (float*)(ws + WS_T);
  unsigned short* kst  = (unsigned short*)(ws + WS_KST);
  unsigned short* vst  = (unsigned short*)(ws + WS_VST);
  unsigned short* k2F  = (unsigned short*)(ws + WS_K2F);
  unsigned short* v2   = (unsigned short*)(ws + WS_V2);
  unsigned short* wqT  = (unsigned short*)(ws + WS_WQT);
  unsigned short* wo_b = (unsigned short*)(ws + WS_WO);
  unsigned short* wgl  = (unsigned short*)(ws + WS_WGL);

  prep_kernel<<<dim3(600), dim3(256), 0, stream>>>(Wq, Wo, ctx, Wk, bk, Wv, bv,
                                                   wqT, wo_b, kst, vst, (float*)ws);
  kv2_kernel<<<dim3(40), dim3(256), 0, stream>>>(wqT, wo_b, kst, vst, bq, tbuf, k2F, v2);
  fusedS_kernel<<<dim3(1728), dim3(256), 0, stream>>>(x, k2F, tbuf, wgl);
  mainH_kernel<<<dim3(1728), dim3(256), 0, stream>>>(x, wgl, v2, bo, accum, out);
  norm_kernel<<<dim3(17280), dim3(256), 0, stream>>>(out, accum, gamma, beta);
}

// Round 15
// 181.665 us; speedup vs baseline: 1.0975x; 1.0042x over previous
//
#include <hip/hip_runtime.h>
#include <hip/hip_bf16.h>

#define B_ 8
#define C_ 320
#define N_ 13824      // 24^3
#define L_ 77
#define LP 80         // L padded for 16-col tiles
#define LV 96         // L padded for K=96 contraction
#define CTXD 768
#define CPG 10        // channels per group (320/32)
#define EPS_ 1e-5f
#define SCALE_ 0.05590169943749474f   // 320^-0.5

typedef __attribute__((__ext_vector_type__(4))) float f32x4;
typedef __attribute__((__ext_vector_type__(8))) short s16x8;

// ws byte offsets
#define WS_ACCUM 0              // f32[8][32][2] = 2048 B
#define WS_T     2048           // f32[8][80]    = 2560 B
#define WS_KST   4608           // bf16[8][80][320] = 409600 B  (k scaled, [l][o])
#define WS_VST   414208         // bf16[8][80][320]             (v, [l][o])
#define WS_K2F   823808         // bf16[8][5][10][512]          (k2 fragment-contig)
#define WS_V2F   1233408        // bf16[8][4][5][3][512] = 245760 B (v2 fragment-contig)
#define WS_WQT   1724928        // bf16[320][320]  Wq transposed [c][o]
#define WS_WO    1929728        // bf16[320][320]  Wo [c'][o]
#define WS_WGF   2134528        // bf16[8][216][3][4][512] = 21233664 B (w fragment-contig)

__device__ __forceinline__ unsigned short f2bf(float f) {
  union { float f; unsigned u; } v; v.f = f;
  unsigned r = v.u + 0x7FFFu + ((v.u >> 16) & 1u);
  return (unsigned short)(r >> 16);
}
__device__ __forceinline__ float bf2f(unsigned short s) {
  union { unsigned u; float f; } v; v.u = ((unsigned)s) << 16;
  return v.f;
}
// load 8 consecutive f32 -> bf16x8 fragment
__device__ __forceinline__ s16x8 cvt8(const float* p) {
  f32x4 a = *reinterpret_cast<const f32x4*>(p);
  f32x4 b = *reinterpret_cast<const f32x4*>(p + 4);
  s16x8 r;
  r[0] = (short)f2bf(a[0]); r[1] = (short)f2bf(a[1]);
  r[2] = (short)f2bf(a[2]); r[3] = (short)f2bf(a[3]);
  r[4] = (short)f2bf(b[0]); r[5] = (short)f2bf(b[1]);
  r[6] = (short)f2bf(b[2]); r[7] = (short)f2bf(b[3]);
  return r;
}
__device__ __forceinline__ f32x4 MFMA(s16x8 a, s16x8 b, f32x4 c) {
  return __builtin_amdgcn_mfma_f32_16x16x32_bf16(a, b, c, 0, 0, 0);
}

// ---------------- PREP: wconv (blocks 0..399) + kv1 l-split (blocks 400..599) --------
__global__ __launch_bounds__(256) void prep_kernel(const float* __restrict__ Wq,
                                                   const float* __restrict__ Wo,
                                                   const float* __restrict__ ctx,
                                                   const float* __restrict__ Wk,
                                                   const float* __restrict__ bk,
                                                   const float* __restrict__ Wv,
                                                   const float* __restrict__ bv,
                                                   unsigned short* __restrict__ wqT,
                                                   unsigned short* __restrict__ wo_bf,
                                                   unsigned short* __restrict__ kst,
                                                   unsigned short* __restrict__ vst,
                                                   float* __restrict__ zws) {
  int bid = blockIdx.x;
  if (bid < 400) {
    int t = bid * 256 + threadIdx.x;
    if (t >= C_ * C_) return;
    int o = t / C_, c = t - o * C_;
    wqT[c * C_ + o] = f2bf(Wq[t]);
    wo_bf[t] = f2bf(Wo[t]);
    return;
  }
  int kb = bid - 400;                       // 0..199
  { int t = kb * 256 + threadIdx.x; if (t < 1152) zws[t] = 0.f; }
  int lt = kb % 5;                          // l-tile 0..4
  int kb5 = kb / 5;                         // 0..39
  int b = kb5 / 5;
  int oc = kb5 % 5;                         // 64-row chunk of outputs
  int w = threadIdx.x >> 6, lane = threadIdx.x & 63;
  int r = lane & 15, h = lane >> 4;
  int o_row = oc * 64 + w * 16 + r;         // A-fragment row
  int l = lt * 16 + r;                      // B col / D col
  bool lok = (l < L_);
  f32x4 ak = {}, av = {};
  for (int ks = 0; ks < 24; ++ks) {
    int c0 = ks * 32 + h * 8;
    s16x8 aWk = cvt8(Wk + o_row * CTXD + c0);
    s16x8 aWv = cvt8(Wv + o_row * CTXD + c0);
    s16x8 bfr = {0,0,0,0,0,0,0,0};
    if (lok) bfr = cvt8(ctx + (b * L_ + l) * CTXD + c0);
    ak = MFMA(aWk, bfr, ak);
    av = MFMA(aWv, bfr, av);
  }
#pragma unroll
  for (int j = 0; j < 4; ++j) {
    int o = oc * 64 + w * 16 + h * 4 + j;
    float bkv = bk[o], bvv = bv[o];
    unsigned short kw = lok ? f2bf(SCALE_ * (ak[j] + bkv)) : (unsigned short)0;
    unsigned short vw = lok ? f2bf(av[j] + bvv) : (unsigned short)0;
    kst[(b * LP + l) * C_ + o] = kw;
    vst[(b * LP + l) * C_ + o] = vw;
  }
}

// ---------------- KV2: k2F = Wq^T k_s (frag); v2F = Wo v_s (frag); t[l] --------------
__global__ __launch_bounds__(256) void kv2_kernel(const unsigned short* __restrict__ wqT,
                                                  const unsigned short* __restrict__ wo_bf,
                                                  const unsigned short* __restrict__ kst,
                                                  const unsigned short* __restrict__ vst,
                                                  const float* __restrict__ bq,
                                                  float* __restrict__ tbuf,
                                                  unsigned short* __restrict__ k2F,
                                                  unsigned short* __restrict__ v2F) {
  int b = blockIdx.x / 5;
  int cc = blockIdx.x % 5;
  int w = threadIdx.x >> 6, lane = threadIdx.x & 63;
  int r = lane & 15, h = lane >> 4;
  int c_row = cc * 64 + w * 16 + r;
  f32x4 a2[5] = {}, av[5] = {};
#pragma unroll
  for (int ks = 0; ks < 10; ++ks) {
    int o0 = ks * 32 + h * 8;
    s16x8 aq = *reinterpret_cast<const s16x8*>(wqT + c_row * C_ + o0);
    s16x8 ao = *reinterpret_cast<const s16x8*>(wo_bf + c_row * C_ + o0);
#pragma unroll
    for (int nt = 0; nt < 5; ++nt) {
      int l = nt * 16 + r;
      s16x8 bk_ = *reinterpret_cast<const s16x8*>(kst + (b * LP + l) * C_ + o0);
      s16x8 bv_ = *reinterpret_cast<const s16x8*>(vst + (b * LP + l) * C_ + o0);
      a2[nt] = MFMA(aq, bk_, a2[nt]);
      av[nt] = MFMA(ao, bv_, av[nt]);
    }
  }
#pragma unroll
  for (int j = 0; j < 4; ++j) {
    int c = cc * 64 + w * 16 + h * 4 + j;     // output channel (D row)
    int ks2 = c >> 5, h2 = (c >> 3) & 3, j2 = c & 7;       // k2F coords (o-dim frag)
    int cs = c / 80, mt = (c - cs * 80) >> 4, rc = c & 15; // v2F coords (c-dim rows)
#pragma unroll
    for (int nt = 0; nt < 5; ++nt) {
      int l = nt * 16 + r;                    // D col
      // k2F: [b][nt][ks][lane = h2*16 + r][j2]; wave load = 1KB contig
      k2F[(((b * 5 + nt) * 10 + ks2) << 9) + ((h2 * 16 + r) << 3) + j2] = f2bf(a2[nt][j]);
      // v2F: [b][cs][mt][ksl][lane = hl*16 + rc][jl], l = ksl*32 + hl*8 + jl
      int ksl = l >> 5, hl = (l >> 3) & 3, jl = l & 7;
      v2F[((((long)(b * 4 + cs) * 5 + mt) * 3 + ksl) << 9) + ((hl * 16 + rc) << 3) + jl]
          = f2bf(av[nt][j]);
    }
  }
  // zero v2F pad region: l in [80,96) = ksl=2, hl>=2 -> elements 256..511 of ks=2 frags.
  // block (b,cc) covers m = c>>4 in [4cc, 4cc+4): 4 (cs,mt) pairs, 256 u16 each.
  {
    int t = threadIdx.x;
    int m = cc * 4 + (t >> 6);            // global 16-chunk index
    int cs = m / 5, mt = m % 5;
    long base = (((long)(b * 4 + cs) * 5 + mt) * 3 + 2) << 9;
    *reinterpret_cast<unsigned long long*>(v2F + base + 256 + (t & 63) * 4) = 0ull;
  }
  // t[l] = sum_o bq[o] * k_s[l][o]
  if (cc == 0 && threadIdx.x < LP) {
    int l = threadIdx.x;
    float acc = 0.f;
    for (int o8 = 0; o8 < C_; o8 += 8) {
      s16x8 kv = *reinterpret_cast<const s16x8*>(kst + (b * LP + l) * C_ + o8);
#pragma unroll
      for (int j = 0; j < 8; ++j) acc += bq[o8 + j] * bf2f((unsigned short)kv[j]);
    }
    tbuf[b * LP + l] = acc;
  }
}

// ---------------- FUSED-S: LDS transpose + GEMM-S + softmax -> wglF fragments --------
__global__ __launch_bounds__(256)
__attribute__((amdgpu_waves_per_eu(2, 3)))
void fusedS_kernel(const float* __restrict__ x,
                   const unsigned short* __restrict__ k2F,
                   const float* __restrict__ tbuf,
                   unsigned short* __restrict__ wglF) {
  __shared__ __align__(16) unsigned short tile[64][344];   // 44032 B (688 B rows)
  char* tb = (char*)&tile[0][0];
  int bid = blockIdx.x;        // 1728 = 8 (XCD-batch) x 216 tiles
  int b = bid & 7;
  int tileIdx = bid >> 3;
  int n0 = tileIdx * 64;
  int tid = threadIdx.x;
  int w = tid >> 6, lane = tid & 63, r = lane & 15, h = lane >> 4;
  const unsigned short* k2f = k2F + ((long)b * 50 << 9);

  // k2F chunk-0 preload issued FIRST: its L2 latency hides under the whole stage phase
  s16x8 kfA[5], kfB[5];
#pragma unroll
  for (int nt = 0; nt < 5; ++nt)
    kfA[nt] = *reinterpret_cast<const s16x8*>(k2f + ((nt * 10) << 9) + (lane << 3));

  // ---- stage x tile transposed into LDS (deep-load batch, swizzled writes) ----
  {
    int s_ = tid & 15;          // n-quad
    int cp = tid >> 4;          // channel pair
    const float* xb = x + (long)b * C_ * N_ + n0 + s_ * 4;
    f32x4 va[10], vb[10];
#pragma unroll
    for (int it = 0; it < 10; ++it) {
      const float* p = xb + (long)(it * 32 + cp * 2) * N_;
      va[it] = *reinterpret_cast<const f32x4*>(p);
      vb[it] = *reinterpret_cast<const f32x4*>(p + N_);
    }
#pragma unroll
    for (int it = 0; it < 10; ++it) {
      int cbyte = (it * 32 + cp * 2) * 2;
#pragma unroll
      for (int q = 0; q < 4; ++q) {
        int row = s_ * 4 + q;
        unsigned pk = (unsigned)f2bf(va[it][q]) | ((unsigned)f2bf(vb[it][q]) << 16);
        *reinterpret_cast<unsigned*>(tb + row * 688 + (cbyte ^ (row & 48))) = pk;
      }
    }
  }
  __syncthreads();

  // ---- GEMM-S: s[16 n/wave][80 l], K=320; A from LDS (swizzled), B = k2F pipeline ----
  int arow = w * 16 + r;
  int abase = arow * 688;
  int akey = arow & 48;        // wave-uniform (= w<<4): read banks unchanged
  f32x4 sacc[5] = {};
#define SCHUNK(KS, KC, KN)                                                      \
  {                                                                             \
    s16x8 a = *reinterpret_cast<const s16x8*>(                                  \
        tb + abase + (((KS * 32 + h * 8) * 2) ^ akey));                         \
    if (KS < 9) {                                                               \
      _Pragma("unroll") for (int nt = 0; nt < 5; ++nt)                          \
          KN[nt] = *reinterpret_cast<const s16x8*>(                             \
              k2f + ((nt * 10 + KS + 1) << 9) + (lane << 3));                   \
    }                                                                           \
    _Pragma("unroll") for (int nt = 0; nt < 5; ++nt)                            \
      sacc[nt] = MFMA(a, KC[nt], sacc[nt]);                                     \
  }
  SCHUNK(0, kfA, kfB) SCHUNK(1, kfB, kfA) SCHUNK(2, kfA, kfB)
  SCHUNK(3, kfB, kfA) SCHUNK(4, kfA, kfB) SCHUNK(5, kfB, kfA)
  SCHUNK(6, kfA, kfB) SCHUNK(7, kfB, kfA) SCHUNK(8, kfA, kfB)
  SCHUNK(9, kfB, kfA)
#undef SCHUNK

  // ---- + t, softmax over l; write fragment-contiguous wglF ----
#pragma unroll
  for (int nt = 0; nt < 5; ++nt) {
    float tl = tbuf[b * LP + nt * 16 + r];
#pragma unroll
    for (int j = 0; j < 4; ++j) sacc[nt][j] += tl;
  }
  long wbase = ((long)(b * 216 + tileIdx) * 12) << 9;   // elements
  bool maskpad = (r >= 13);   // col 64+r >= 77
#pragma unroll
  for (int j = 0; j < 4; ++j) {
    float m = -1e30f;
#pragma unroll
    for (int nt = 0; nt < 5; ++nt) {
      float v = (nt == 4 && maskpad) ? -1e30f : sacc[nt][j];
      m = fmaxf(m, v);
    }
    for (int d = 1; d < 16; d <<= 1) m = fmaxf(m, __shfl_xor(m, d));
    float e[5]; float sum = 0.f;
#pragma unroll
    for (int nt = 0; nt < 5; ++nt) {
      float v = (nt == 4 && maskpad) ? 0.f : __expf(sacc[nt][j] - m);
      e[nt] = v; sum += v;
    }
    for (int d = 1; d < 16; d <<= 1) sum += __shfl_xor(sum, d);
    float inv = 1.f / sum;
    int r2 = h * 4 + j;         // consumer row-within-frag (n = w*16 + r2)
#pragma unroll
    for (int nt = 0; nt < 5; ++nt) {
      int l = nt * 16 + r;
      int ks = l >> 5, h2 = (l >> 3) & 3, j2 = l & 7;
      wglF[wbase + ((ks * 4 + w) << 9) + ((h2 * 16 + r2) << 3) + j2] = f2bf(e[nt] * inv);
    }
  }
  // zero pad region: l in [80,96) = ks=2 frags (nt4 0..3), elements 256..511
  {
    int t = tid;
    *reinterpret_cast<unsigned long long*>(
        wglF + wbase + ((2 * 4 + (t >> 6)) << 9) + 256 + (t & 63) * 4) = 0ull;
  }
}

// ---------------- MAIN-H: GEMM h = v2 . w^T, ALL operand loads fragment-contiguous ---
__global__ __launch_bounds__(256)
__attribute__((amdgpu_waves_per_eu(2, 3)))
void mainH_kernel(const float* __restrict__ x,
                  const unsigned short* __restrict__ wglF,
                  const unsigned short* __restrict__ v2F,
                  const float* __restrict__ bo,
                  float* __restrict__ accum,
                  float* __restrict__ hout) {
  __shared__ float ch[C_][2];
  int bid = blockIdx.x;        // 1728 = 8 x 216
  int b = bid & 7;
  int tileIdx = bid >> 3;
  int n0 = tileIdx * 64;
  int tid = threadIdx.x;
  int w = tid >> 6, lane = tid & 63, r = lane & 15, h = lane >> 4;
  const unsigned short* wf = wglF + (((long)(b * 216 + tileIdx) * 12) << 9);
  const unsigned short* vf = v2F + (((long)(b * 4 + w) * 15) << 9);   // wave w = c-strip
  const float* xb = x + (long)b * C_ * N_ + n0;

  f32x4 acc[4][5] = {};   // [nt][mt]: wave covers 80 c x 64 n
#pragma unroll
  for (int ks = 0; ks < 3; ++ks) {
    s16x8 bf[4];
#pragma unroll
    for (int nt = 0; nt < 4; ++nt)
      bf[nt] = *reinterpret_cast<const s16x8*>(wf + ((ks * 4 + nt) << 9) + (lane << 3));
#pragma unroll
    for (int mt = 0; mt < 5; ++mt) {
      s16x8 va = *reinterpret_cast<const s16x8*>(vf + ((mt * 3 + ks) << 9) + (lane << 3));
#pragma unroll
      for (int nt = 0; nt < 4; ++nt) acc[nt][mt] = MFMA(va, bf[nt], acc[nt][mt]);
    }
  }
  // ---- epilogue: + bo + residual (f32, L3-hot), bf16 packed store, group stats ----
#pragma unroll
  for (int mt = 0; mt < 5; ++mt) {
    int cb = w * 80 + mt * 16 + h * 4;
    float bov[4];
#pragma unroll
    for (int j = 0; j < 4; ++j) bov[j] = bo[cb + j];
    float sv[4] = {0.f, 0.f, 0.f, 0.f}, sq[4] = {0.f, 0.f, 0.f, 0.f};
#pragma unroll
    for (int nt = 0; nt < 4; ++nt) {
      int n = nt * 16 + r;
#pragma unroll
      for (int j = 0; j < 4; ++j) {
        float val = acc[nt][mt][j] + bov[j] + xb[(long)(cb + j) * N_ + n];
        long e = ((long)b * C_ + cb + j) * N_ + n0 + n;
        *reinterpret_cast<unsigned short*>(
            (char*)hout + ((e >> 11) << 13) + ((e & 2047) << 1)) = f2bf(val);
        sv[j] += val; sq[j] += val * val;
      }
    }
#pragma unroll
    for (int j = 0; j < 4; ++j) {
      for (int d = 1; d < 16; d <<= 1) {
        sv[j] += __shfl_xor(sv[j], d);
        sq[j] += __shfl_xor(sq[j], d);
      }
      if (r == 0) { ch[cb + j][0] = sv[j]; ch[cb + j][1] = sq[j]; }
    }
  }
  __syncthreads();
  if (tid < 32) {
    float s0 = 0.f, s1 = 0.f;
#pragma unroll
    for (int i = 0; i < CPG; ++i) { s0 += ch[tid * CPG + i][0]; s1 += ch[tid * CPG + i][1]; }
    atomicAdd(&accum[b * 64 + tid * 2], s0);
    atomicAdd(&accum[b * 64 + tid * 2 + 1], s1);
  }
}

// ---------------- normalize + affine + swish: bf16 packed in -> f32 NT out ----------
__global__ __launch_bounds__(256) void norm_kernel(float* __restrict__ hout,
                                                   const float* __restrict__ accum,
                                                   const float* __restrict__ gamma,
                                                   const float* __restrict__ beta) {
  long idx0 = (long)blockIdx.x * 2048;
  int t = threadIdx.x;
  s16x8 hv = *reinterpret_cast<const s16x8*>((const char*)hout + idx0 * 4 + t * 16);
  __syncthreads();   // all bf16 reads complete before any f32 overwrite (intra-chunk)
  long idx = idx0 + (long)t * 8;
  int b = (int)(idx / ((long)C_ * N_));
  long rem = idx - (long)b * C_ * N_;
  int c = (int)(rem / N_);
  int g = c / CPG;
  float s0 = accum[b * 64 + g * 2], s1 = accum[b * 64 + g * 2 + 1];
  const float invc = 1.f / 138240.f;   // 1 / (CPG * N_)
  float mu = s0 * invc;
  float var = s1 * invc - mu * mu;
  float rstd = rsqrtf(var + EPS_);
  float ga = gamma[c], be = beta[c];
  f32x4 v0, v1;
#pragma unroll
  for (int q = 0; q < 4; ++q) {
    float y = (bf2f((unsigned short)hv[q]) - mu) * rstd * ga + be;
    v0[q] = y / (1.f + __expf(-y));
    float z = (bf2f((unsigned short)hv[q + 4]) - mu) * rstd * ga + be;
    v1[q] = z / (1.f + __expf(-z));
  }
  __builtin_nontemporal_store(v0, reinterpret_cast<f32x4*>(hout + idx));
  __builtin_nontemporal_store(v1, reinterpret_cast<f32x4*>(hout + idx + 4));
}

extern "C" void kernel_launch(void* const* d_in, const int* in_sizes, int n_in,
                              void* d_out, int out_size, void* d_ws, size_t ws_size,
                              hipStream_t stream) {
  const float* x     = (const float*)d_in[0];
  const float* ctx   = (const float*)d_in[1];
  const float* Wq    = (const float*)d_in[2];
  const float* bq    = (const float*)d_in[3];
  const float* Wk    = (const float*)d_in[4];
  const float* bk    = (const float*)d_in[5];
  const float* Wv    = (const float*)d_in[6];
  const float* bv    = (const float*)d_in[7];
  const float* Wo    = (const float*)d_in[8];
  const float* bo    = (const float*)d_in[9];
  const float* gamma = (const float*)d_in[10];
  const float* beta  = (const float*)d_in[11];
  float* out = (float*)d_out;
  char* ws = (char*)d_ws;

  float* accum = (float*)(ws + WS_ACCUM);
  float* tbuf  = (float*)(ws + WS_T);
  unsigned short* kst  = (unsigned short*)(ws + WS_KST);
  unsigned short* vst  = (unsigned short*)(ws + WS_VST);
  unsigned short* k2F  = (unsigned short*)(ws + WS_K2F);
  unsigned short* v2F  = (unsigned short*)(ws + WS_V2F);
  unsigned short* wqT  = (unsigned short*)(ws + WS_WQT);
  unsigned short* wo_b = (unsigned short*)(ws + WS_WO);
  unsigned short* wglF = (unsigned short*)(ws + WS_WGF);

  prep_kernel<<<dim3(600), dim3(256), 0, stream>>>(Wq, Wo, ctx, Wk, bk, Wv, bv,
                                                   wqT, wo_b, kst, vst, (float*)ws);
  kv2_kernel<<<dim3(40), dim3(256), 0, stream>>>(wqT, wo_b, kst, vst, bq, tbuf, k2F, v2F);
  fusedS_kernel<<<dim3(1728), dim3(256), 0, stream>>>(x, k2F, tbuf, wglF);
  mainH_kernel<<<dim3(1728), dim3(256), 0, stream>>>(x, wglF, v2F, bo, accum, out);
  norm_kernel<<<dim3(17280), dim3(256), 0, stream>>>(out, accum, gamma, beta);
}

// Round 16
// 166.886 us; speedup vs baseline: 1.1947x; 1.0886x over previous
//
#include <hip/hip_runtime.h>
#include <hip/hip_bf16.h>

#define B_ 8
#define C_ 320
#define N_ 13824      // 24^3
#define L_ 77
#define LP 80         // L padded for 16-col tiles
#define LV 96         // L padded for K=96 contraction
#define CTXD 768
#define CPG 10        // channels per group (320/32)
#define EPS_ 1e-5f
#define SCALE_ 0.05590169943749474f   // 320^-0.5

typedef __attribute__((__ext_vector_type__(4))) float f32x4;
typedef __attribute__((__ext_vector_type__(8))) short s16x8;

// ws byte offsets
#define WS_ACCUM 0              // f32[8][32][2] = 2048 B
#define WS_T     2048           // f32[8][80]    = 2560 B
#define WS_KST   4608           // bf16[8][80][320] = 409600 B  (k scaled, [l][o])
#define WS_VST   414208         // bf16[8][80][320]             (v, [l][o])
#define WS_K2F   823808         // bf16[8][5][10][512]          (k2 fragment-contig)
#define WS_V2F   1233408        // bf16[8][4][5][3][512] = 245760 B (v2 fragment-contig)
#define WS_WQT   1724928        // bf16[320][320]  Wq transposed [c][o]
#define WS_WO    1929728        // bf16[320][320]  Wo [c'][o]

__device__ __forceinline__ unsigned short f2bf(float f) {
  union { float f; unsigned u; } v; v.f = f;
  unsigned r = v.u + 0x7FFFu + ((v.u >> 16) & 1u);
  return (unsigned short)(r >> 16);
}
__device__ __forceinline__ float bf2f(unsigned short s) {
  union { unsigned u; float f; } v; v.u = ((unsigned)s) << 16;
  return v.f;
}
// load 8 consecutive f32 -> bf16x8 fragment
__device__ __forceinline__ s16x8 cvt8(const float* p) {
  f32x4 a = *reinterpret_cast<const f32x4*>(p);
  f32x4 b = *reinterpret_cast<const f32x4*>(p + 4);
  s16x8 r;
  r[0] = (short)f2bf(a[0]); r[1] = (short)f2bf(a[1]);
  r[2] = (short)f2bf(a[2]); r[3] = (short)f2bf(a[3]);
  r[4] = (short)f2bf(b[0]); r[5] = (short)f2bf(b[1]);
  r[6] = (short)f2bf(b[2]); r[7] = (short)f2bf(b[3]);
  return r;
}
__device__ __forceinline__ f32x4 MFMA(s16x8 a, s16x8 b, f32x4 c) {
  return __builtin_amdgcn_mfma_f32_16x16x32_bf16(a, b, c, 0, 0, 0);
}

// ---------------- PREP: wconv (blocks 0..399) + kv1 l-split (blocks 400..599) --------
__global__ __launch_bounds__(256) void prep_kernel(const float* __restrict__ Wq,
                                                   const float* __restrict__ Wo,
                                                   const float* __restrict__ ctx,
                                                   const float* __restrict__ Wk,
                                                   const float* __restrict__ bk,
                                                   const float* __restrict__ Wv,
                                                   const float* __restrict__ bv,
                                                   unsigned short* __restrict__ wqT,
                                                   unsigned short* __restrict__ wo_bf,
                                                   unsigned short* __restrict__ kst,
                                                   unsigned short* __restrict__ vst,
                                                   float* __restrict__ zws) {
  int bid = blockIdx.x;
  if (bid < 400) {
    int t = bid * 256 + threadIdx.x;
    if (t >= C_ * C_) return;
    int o = t / C_, c = t - o * C_;
    wqT[c * C_ + o] = f2bf(Wq[t]);
    wo_bf[t] = f2bf(Wo[t]);
    return;
  }
  int kb = bid - 400;                       // 0..199
  { int t = kb * 256 + threadIdx.x; if (t < 1152) zws[t] = 0.f; }
  int lt = kb % 5;                          // l-tile 0..4
  int kb5 = kb / 5;                         // 0..39
  int b = kb5 / 5;
  int oc = kb5 % 5;                         // 64-row chunk of outputs
  int w = threadIdx.x >> 6, lane = threadIdx.x & 63;
  int r = lane & 15, h = lane >> 4;
  int o_row = oc * 64 + w * 16 + r;         // A-fragment row
  int l = lt * 16 + r;                      // B col / D col
  bool lok = (l < L_);
  f32x4 ak = {}, av = {};
  for (int ks = 0; ks < 24; ++ks) {
    int c0 = ks * 32 + h * 8;
    s16x8 aWk = cvt8(Wk + o_row * CTXD + c0);
    s16x8 aWv = cvt8(Wv + o_row * CTXD + c0);
    s16x8 bfr = {0,0,0,0,0,0,0,0};
    if (lok) bfr = cvt8(ctx + (b * L_ + l) * CTXD + c0);
    ak = MFMA(aWk, bfr, ak);
    av = MFMA(aWv, bfr, av);
  }
#pragma unroll
  for (int j = 0; j < 4; ++j) {
    int o = oc * 64 + w * 16 + h * 4 + j;
    float bkv = bk[o], bvv = bv[o];
    unsigned short kw = lok ? f2bf(SCALE_ * (ak[j] + bkv)) : (unsigned short)0;
    unsigned short vw = lok ? f2bf(av[j] + bvv) : (unsigned short)0;
    kst[(b * LP + l) * C_ + o] = kw;
    vst[(b * LP + l) * C_ + o] = vw;
  }
}

// ---------------- KV2: k2F = Wq^T k_s (frag); v2F = Wo v_s (frag); t[l] --------------
__global__ __launch_bounds__(256) void kv2_kernel(const unsigned short* __restrict__ wqT,
                                                  const unsigned short* __restrict__ wo_bf,
                                                  const unsigned short* __restrict__ kst,
                                                  const unsigned short* __restrict__ vst,
                                                  const float* __restrict__ bq,
                                                  float* __restrict__ tbuf,
                                                  unsigned short* __restrict__ k2F,
                                                  unsigned short* __restrict__ v2F) {
  int b = blockIdx.x / 5;
  int cc = blockIdx.x % 5;
  int w = threadIdx.x >> 6, lane = threadIdx.x & 63;
  int r = lane & 15, h = lane >> 4;
  int c_row = cc * 64 + w * 16 + r;
  f32x4 a2[5] = {}, av[5] = {};
#pragma unroll
  for (int ks = 0; ks < 10; ++ks) {
    int o0 = ks * 32 + h * 8;
    s16x8 aq = *reinterpret_cast<const s16x8*>(wqT + c_row * C_ + o0);
    s16x8 ao = *reinterpret_cast<const s16x8*>(wo_bf + c_row * C_ + o0);
#pragma unroll
    for (int nt = 0; nt < 5; ++nt) {
      int l = nt * 16 + r;
      s16x8 bk_ = *reinterpret_cast<const s16x8*>(kst + (b * LP + l) * C_ + o0);
      s16x8 bv_ = *reinterpret_cast<const s16x8*>(vst + (b * LP + l) * C_ + o0);
      a2[nt] = MFMA(aq, bk_, a2[nt]);
      av[nt] = MFMA(ao, bv_, av[nt]);
    }
  }
#pragma unroll
  for (int j = 0; j < 4; ++j) {
    int c = cc * 64 + w * 16 + h * 4 + j;     // output channel (D row)
    int ks2 = c >> 5, h2 = (c >> 3) & 3, j2 = c & 7;       // k2F coords (o-dim frag)
    int cs = c / 80, mt = (c - cs * 80) >> 4, rc = c & 15; // v2F coords (c-dim rows)
#pragma unroll
    for (int nt = 0; nt < 5; ++nt) {
      int l = nt * 16 + r;                    // D col
      // k2F: [b][nt][ks][lane = h2*16 + r][j2]; wave load = 1KB contig
      k2F[(((b * 5 + nt) * 10 + ks2) << 9) + ((h2 * 16 + r) << 3) + j2] = f2bf(a2[nt][j]);
      // v2F: [b][cs][mt][ksl][lane = hl*16 + rc][jl], l = ksl*32 + hl*8 + jl
      int ksl = l >> 5, hl = (l >> 3) & 3, jl = l & 7;
      v2F[((((long)(b * 4 + cs) * 5 + mt) * 3 + ksl) << 9) + ((hl * 16 + rc) << 3) + jl]
          = f2bf(av[nt][j]);
    }
  }
  // zero v2F pad region: l in [80,96) = ksl=2, hl>=2 -> elements 256..511 of ks=2 frags.
  {
    int t = threadIdx.x;
    int m = cc * 4 + (t >> 6);            // global 16-chunk index
    int cs = m / 5, mt = m % 5;
    long base = (((long)(b * 4 + cs) * 5 + mt) * 3 + 2) << 9;
    *reinterpret_cast<unsigned long long*>(v2F + base + 256 + (t & 63) * 4) = 0ull;
  }
  // t[l] = sum_o bq[o] * k_s[l][o]
  if (cc == 0 && threadIdx.x < LP) {
    int l = threadIdx.x;
    float acc = 0.f;
    for (int o8 = 0; o8 < C_; o8 += 8) {
      s16x8 kv = *reinterpret_cast<const s16x8*>(kst + (b * LP + l) * C_ + o8);
#pragma unroll
      for (int j = 0; j < 8; ++j) acc += bq[o8 + j] * bf2f((unsigned short)kv[j]);
    }
    tbuf[b * LP + l] = acc;
  }
}

// ---------------- FUSED: transpose + GEMM-S + softmax(P->LDS) + GEMM-H + epilogue ----
// One x read total: LDS tile serves GEMM-S A-operand AND the residual (bf16).
// P passes through 12 KB LDS (no global wgl round-trip). All GEMM operand loads
// fragment-contiguous (k2F from L2, v2F from L2, P from LDS).
__global__ __launch_bounds__(256)
__attribute__((amdgpu_waves_per_eu(2, 3)))
void fused_kernel(const float* __restrict__ x,
                  const unsigned short* __restrict__ k2F,
                  const unsigned short* __restrict__ v2F,
                  const float* __restrict__ tbuf,
                  const float* __restrict__ bo,
                  float* __restrict__ accum,
                  float* __restrict__ hout) {
  __shared__ __align__(16) unsigned short tile[64][344];   // 44032 B (688 B rows)
  __shared__ __align__(16) unsigned short pw[12][512];     // 12288 B (P fragments)
  __shared__ float ch[C_][2];                              // 2560 B   total 58880 B
  char* tb = (char*)&tile[0][0];
  int bid = blockIdx.x;        // 1728 = 8 (XCD-batch) x 216 tiles
  int b = bid & 7;
  int n0 = (bid >> 3) * 64;
  int tid = threadIdx.x;
  int w = tid >> 6, lane = tid & 63, r = lane & 15, h = lane >> 4;
  const unsigned short* k2f = k2F + ((long)b * 50 << 9);

  // k2F chunk-0 preload issued FIRST: its L2 latency hides under the whole stage phase
  s16x8 kfA[5], kfB[5];
#pragma unroll
  for (int nt = 0; nt < 5; ++nt)
    kfA[nt] = *reinterpret_cast<const s16x8*>(k2f + ((nt * 10) << 9) + (lane << 3));

  // ---- stage x tile transposed into LDS (deep-load batch, swizzled writes) ----
  {
    int s_ = tid & 15;          // n-quad
    int cp = tid >> 4;          // channel pair
    const float* xb = x + (long)b * C_ * N_ + n0 + s_ * 4;
    f32x4 va[10], vb[10];
#pragma unroll
    for (int it = 0; it < 10; ++it) {
      const float* p = xb + (long)(it * 32 + cp * 2) * N_;
      va[it] = *reinterpret_cast<const f32x4*>(p);
      vb[it] = *reinterpret_cast<const f32x4*>(p + N_);
    }
#pragma unroll
    for (int it = 0; it < 10; ++it) {
      int cbyte = (it * 32 + cp * 2) * 2;
#pragma unroll
      for (int q = 0; q < 4; ++q) {
        int row = s_ * 4 + q;
        unsigned pk = (unsigned)f2bf(va[it][q]) | ((unsigned)f2bf(vb[it][q]) << 16);
        *reinterpret_cast<unsigned*>(tb + row * 688 + (cbyte ^ (row & 48))) = pk;
      }
    }
  }
  // zero pw pad region: l in [80,96) = ks=2 frags, elements 256..511 (before barrier)
  *reinterpret_cast<unsigned long long*>(&pw[8 + (tid >> 6)][256 + (tid & 63) * 4]) = 0ull;
  __syncthreads();

  // ---- GEMM-S: s[16 n/wave][80 l], K=320; A from LDS (swizzled), B = k2F pipeline ----
  int arow = w * 16 + r;
  int abase = arow * 688;
  int akey = arow & 48;        // wave-uniform (= w<<4): read banks unchanged
  f32x4 sacc[5] = {};
#define SCHUNK(KS, KC, KN)                                                      \
  {                                                                             \
    s16x8 a = *reinterpret_cast<const s16x8*>(                                  \
        tb + abase + (((KS * 32 + h * 8) * 2) ^ akey));                         \
    if (KS < 9) {                                                               \
      _Pragma("unroll") for (int nt = 0; nt < 5; ++nt)                          \
          KN[nt] = *reinterpret_cast<const s16x8*>(                             \
              k2f + ((nt * 10 + KS + 1) << 9) + (lane << 3));                   \
    }                                                                           \
    _Pragma("unroll") for (int nt = 0; nt < 5; ++nt)                            \
      sacc[nt] = MFMA(a, KC[nt], sacc[nt]);                                     \
  }
  SCHUNK(0, kfA, kfB) SCHUNK(1, kfB, kfA) SCHUNK(2, kfA, kfB)
  SCHUNK(3, kfB, kfA) SCHUNK(4, kfA, kfB) SCHUNK(5, kfB, kfA)
  SCHUNK(6, kfA, kfB) SCHUNK(7, kfB, kfA) SCHUNK(8, kfA, kfB)
  SCHUNK(9, kfB, kfA)
#undef SCHUNK

  // ---- + t, softmax over l; write P fragments into LDS pw ----
#pragma unroll
  for (int nt = 0; nt < 5; ++nt) {
    float tl = tbuf[b * LP + nt * 16 + r];
#pragma unroll
    for (int j = 0; j < 4; ++j) sacc[nt][j] += tl;
  }
  bool maskpad = (r >= 13);   // col 64+r >= 77
#pragma unroll
  for (int j = 0; j < 4; ++j) {
    float m = -1e30f;
#pragma unroll
    for (int nt = 0; nt < 5; ++nt) {
      float v = (nt == 4 && maskpad) ? -1e30f : sacc[nt][j];
      m = fmaxf(m, v);
    }
    for (int d = 1; d < 16; d <<= 1) m = fmaxf(m, __shfl_xor(m, d));
    float e[5]; float sum = 0.f;
#pragma unroll
    for (int nt = 0; nt < 5; ++nt) {
      float v = (nt == 4 && maskpad) ? 0.f : __expf(sacc[nt][j] - m);
      e[nt] = v; sum += v;
    }
    for (int d = 1; d < 16; d <<= 1) sum += __shfl_xor(sum, d);
    float inv = 1.f / sum;
    int r2 = h * 4 + j;         // consumer row-within-frag (n = w*16 + r2)
#pragma unroll
    for (int nt = 0; nt < 5; ++nt) {
      int l = nt * 16 + r;
      int ks = l >> 5, h2 = (l >> 3) & 3, j2 = l & 7;
      pw[ks * 4 + w][((h2 * 16 + r2) << 3) + j2] = f2bf(e[nt] * inv);
    }
  }
  __syncthreads();

  // ---- GEMM-H: wave w = c-strip [80w, 80w+80); h[80 c][64 n], K=96 over l ----
  const unsigned short* vf = v2F + (((long)(b * 4 + w) * 15) << 9);
  f32x4 acc[4][5] = {};   // [nt][mt]
#pragma unroll
  for (int ks = 0; ks < 3; ++ks) {
    s16x8 bf[4];
#pragma unroll
    for (int nt = 0; nt < 4; ++nt)
      bf[nt] = *reinterpret_cast<const s16x8*>(&pw[ks * 4 + nt][lane << 3]);
#pragma unroll
    for (int mt = 0; mt < 5; ++mt) {
      s16x8 va = *reinterpret_cast<const s16x8*>(vf + ((mt * 3 + ks) << 9) + (lane << 3));
#pragma unroll
      for (int nt = 0; nt < 4; ++nt) acc[nt][mt] = MFMA(va, bf[nt], acc[nt][mt]);
    }
  }
  // ---- epilogue: + bo + residual (bf16 from LDS tile), bf16 packed store, stats ----
#pragma unroll
  for (int mt = 0; mt < 5; ++mt) {
    int cb = w * 80 + mt * 16 + h * 4;
    int cbyte = cb * 2;
    float bov[4];
#pragma unroll
    for (int j = 0; j < 4; ++j) bov[j] = bo[cb + j];
    float sv[4] = {0.f, 0.f, 0.f, 0.f}, sq[4] = {0.f, 0.f, 0.f, 0.f};
#pragma unroll
    for (int nt = 0; nt < 4; ++nt) {
      int n = nt * 16 + r;
      // residual from LDS tile: 4 bf16 at row n, col cb (swizzle key wave-uniform per nt)
      unsigned long long xr4 = *reinterpret_cast<const unsigned long long*>(
          tb + n * 688 + (cbyte ^ (n & 48)));
#pragma unroll
      for (int j = 0; j < 4; ++j) {
        float val = acc[nt][mt][j] + bov[j] + bf2f((unsigned short)(xr4 >> (j * 16)));
        long e = ((long)b * C_ + cb + j) * N_ + n0 + n;
        *reinterpret_cast<unsigned short*>(
            (char*)hout + ((e >> 11) << 13) + ((e & 2047) << 1)) = f2bf(val);
        sv[j] += val; sq[j] += val * val;
      }
    }
#pragma unroll
    for (int j = 0; j < 4; ++j) {
      for (int d = 1; d < 16; d <<= 1) {
        sv[j] += __shfl_xor(sv[j], d);
        sq[j] += __shfl_xor(sq[j], d);
      }
      if (r == 0) { ch[cb + j][0] = sv[j]; ch[cb + j][1] = sq[j]; }
    }
  }
  __syncthreads();
  if (tid < 32) {
    float s0 = 0.f, s1 = 0.f;
#pragma unroll
    for (int i = 0; i < CPG; ++i) { s0 += ch[tid * CPG + i][0]; s1 += ch[tid * CPG + i][1]; }
    atomicAdd(&accum[b * 64 + tid * 2], s0);
    atomicAdd(&accum[b * 64 + tid * 2 + 1], s1);
  }
}

// ---------------- normalize + affine + swish: bf16 packed in -> f32 NT out ----------
__global__ __launch_bounds__(256) void norm_kernel(float* __restrict__ hout,
                                                   const float* __restrict__ accum,
                                                   const float* __restrict__ gamma,
                                                   const float* __restrict__ beta) {
  long idx0 = (long)blockIdx.x * 2048;
  int t = threadIdx.x;
  s16x8 hv = *reinterpret_cast<const s16x8*>((const char*)hout + idx0 * 4 + t * 16);
  __syncthreads();   // all bf16 reads complete before any f32 overwrite (intra-chunk)
  long idx = idx0 + (long)t * 8;
  int b = (int)(idx / ((long)C_ * N_));
  long rem = idx - (long)b * C_ * N_;
  int c = (int)(rem / N_);
  int g = c / CPG;
  float s0 = accum[b * 64 + g * 2], s1 = accum[b * 64 + g * 2 + 1];
  const float invc = 1.f / 138240.f;   // 1 / (CPG * N_)
  float mu = s0 * invc;
  float var = s1 * invc - mu * mu;
  float rstd = rsqrtf(var + EPS_);
  float ga = gamma[c], be = beta[c];
  f32x4 v0, v1;
#pragma unroll
  for (int q = 0; q < 4; ++q) {
    float y = (bf2f((unsigned short)hv[q]) - mu) * rstd * ga + be;
    v0[q] = y / (1.f + __expf(-y));
    float z = (bf2f((unsigned short)hv[q + 4]) - mu) * rstd * ga + be;
    v1[q] = z / (1.f + __expf(-z));
  }
  __builtin_nontemporal_store(v0, reinterpret_cast<f32x4*>(hout + idx));
  __builtin_nontemporal_store(v1, reinterpret_cast<f32x4*>(hout + idx + 4));
}

extern "C" void kernel_launch(void* const* d_in, const int* in_sizes, int n_in,
                              void* d_out, int out_size, void* d_ws, size_t ws_size,
                              hipStream_t stream) {
  const float* x     = (const float*)d_in[0];
  const float* ctx   = (const float*)d_in[1];
  const float* Wq    = (const float*)d_in[2];
  const float* bq    = (const float*)d_in[3];
  const float* Wk    = (const float*)d_in[4];
  const float* bk    = (const float*)d_in[5];
  const float* Wv    = (const float*)d_in[6];
  const float* bv    = (const float*)d_in[7];
  const float* Wo    = (const float*)d_in[8];
  const float* bo    = (const float*)d_in[9];
  const float* gamma = (const float*)d_in[10];
  const float* beta  = (const float*)d_in[11];
  float* out = (float*)d_out;
  char* ws = (char*)d_ws;

  float* accum = (float*)(ws + WS_ACCUM);
  float* tbuf  = (float*)(ws + WS_T);
  unsigned short* kst  = (unsigned short*)(ws + WS_KST);
  unsigned short* vst  = (unsigned short*)(ws + WS_VST);
  unsigned short* k2F  = (unsigned short*)(ws + WS_K2F);
  unsigned short* v2F  = (unsigned short*)(ws + WS_V2F);
  unsigned short* wqT  = (unsigned short*)(ws + WS_WQT);
  unsigned short* wo_b = (unsigned short*)(ws + WS_WO);

  prep_kernel<<<dim3(600), dim3(256), 0, stream>>>(Wq, Wo, ctx, Wk, bk, Wv, bv,
                                                   wqT, wo_b, kst, vst, (float*)ws);
  kv2_kernel<<<dim3(40), dim3(256), 0, stream>>>(wqT, wo_b, kst, vst, bq, tbuf, k2F, v2F);
  fused_kernel<<<dim3(1728), dim3(256), 0, stream>>>(x, k2F, v2F, tbuf, bo, accum, out);
  norm_kernel<<<dim3(17280), dim3(256), 0, stream>>>(out, accum, gamma, beta);
}